// Round 1
// 209.987 us; speedup vs baseline: 1.0045x; 1.0045x over previous
//
#include <hip/hip_runtime.h>

// OTAM soft-DTW cumulative distance, exp-space chunked affine scan, f32 + DPP.
//
// Exp space, F[m] = exp(-2*cum[m]) (lambda = 0.5):
//   row l>=1:  F[m] = alpha_m * F[m-1] + beta_m
//     alpha_m = exp(-2*d[l][m-1]) = exp2(K*d), K = -2*log2(e)  (single mul+exp)
//     beta_1  = alpha_1 * (S + P[1])   (prev[0]=0 -> S; cur[0]=0 enters as y0=S)
//     beta_m  = alpha_m * P[m-1]
//     col 49  : F49 = F[48] + P[48] + F49_prev   (accumulator, lane 15)
//   row 0: plain cumprod of alpha.
// Stored units: true = stored * 2^offE; S = 2^-offE is the stored 1.0 (exact
// power of two). Renorm every 8 rows (after odd blocks) by group-max exponent;
// renorm scaling is an exact power of 2 so cadence does not change rounding.
//
// Layout change vs previous version: 16 lanes/problem, 3 cols per lane
// (cols 3k+1..3k+3) -> ALL 64 lanes useful (was 12 of 16 = 25% idle issue).
// Loads are 3 dwords per row per lane (bytes [12k,12k+12) of each 192B row);
// union per 16-lane group is the same contiguous 192B, so HBM lines fetched
// are identical to the old float4 scheme.
//
// Renorm group-max via DPP butterfly (quad_perm^1, quad_perm^2, half_mirror,
// mirror) -> every lane holds the 16-lane max; no ds_swizzle, no LDS at all.
//
// Pipeline: blocks of 4 rows; 3 register buffers A,B,C rotating with
// load-3-blocks-ahead, same proven structure as before.

template<int CTRL>
__device__ __forceinline__ float dpp_mov(float src, float old) {
    return __int_as_float(__builtin_amdgcn_update_dpp(
        __float_as_int(old), __float_as_int(src), CTRL, 0xF, 0xF, false));
}

__device__ __forceinline__ float fast_exp2(float x) {
#if __has_builtin(__builtin_amdgcn_exp2f)
    return __builtin_amdgcn_exp2f(x);
#else
    return exp2f(x);
#endif
}

#define KEXP (-2.88539008177792681472f)  // -2*log2(e)

__global__ __launch_bounds__(256, 4) void otam_kernel(const float* __restrict__ dists,
                                                      float* __restrict__ out) {
    const int t = blockIdx.x * 256 + threadIdx.x;
    const int k = t & 15;     // lane within 16-lane group (DPP row)
    const int prob = t >> 4;  // 0..16383

    const float* __restrict__ base = dists + (size_t)prob * 2304 + 3 * k;

    float P0, P1, P2;         // F_prev at cols 3k+1..3k+3 (stored units)
    float F49 = 0.0f;         // col-49 accumulator (lane 15's is real)
    float S = 1.0f;           // stored rep of true 1.0 ( = 2^-offE )
    int offE = 0;

    auto do_row = [&](float qx, float qy, float qz) {
        float a0 = fast_exp2(KEXP * qx);
        float a1 = fast_exp2(KEXP * qy);
        float a2 = fast_exp2(KEXP * qz);

        // lane k gets F_prev[3k] from lane k-1's P2; lane 0 keeps old = S+P0
        // (edge m==1: beta_1 = a1*(F_prev[0] + F_prev[1]) = a1*(S + P0))
        float Plast = dpp_mov<0x111>(P2, S + P0);
        float be0 = a0 * Plast;
        float be1 = a1 * P0;
        float be2 = a2 * P1;
        float PoldLast = P2;                    // F_prev[48] on lane 15

        float Ap0 = a0,       Bp0 = be0;
        float Ap1 = a1 * Ap0, Bp1 = fmaf(a1, Bp0, be1);
        float Ap2 = a2 * Ap1, Bp2 = fmaf(a2, Bp1, be2);

        // inclusive Hillis-Steele affine scan over 16 lanes via DPP
        float A = Ap2, B = Bp2;
        { float Au = dpp_mov<0x111>(A, 1.0f), Bu = dpp_mov<0x111>(B, 0.0f);
          B = fmaf(A, Bu, B); A *= Au; }
        { float Au = dpp_mov<0x112>(A, 1.0f), Bu = dpp_mov<0x112>(B, 0.0f);
          B = fmaf(A, Bu, B); A *= Au; }
        { float Au = dpp_mov<0x114>(A, 1.0f), Bu = dpp_mov<0x114>(B, 0.0f);
          B = fmaf(A, Bu, B); A *= Au; }
        { float Au = dpp_mov<0x118>(A, 1.0f), Bu = dpp_mov<0x118>(B, 0.0f);
          B = fmaf(A, Bu, B); A *= Au; }

        float incl = fmaf(A, S, B);          // inclusive applied to y0=S
        float yin = dpp_mov<0x111>(incl, S); // lane 0 gets S via `old`

        P0 = fmaf(Ap0, yin, Bp0);
        P1 = fmaf(Ap1, yin, Bp1);
        P2 = fmaf(Ap2, yin, Bp2);

        F49 = P2 + PoldLast + F49;           // meaningful on lane 15 only
    };

    auto renorm = [&]() {
        float m = fmaxf(fmaxf(P0, P1), P2);
        m = fmaxf(m, dpp_mov<0xB1>(m, m));   // quad_perm [1,0,3,2]  (lane^1)
        m = fmaxf(m, dpp_mov<0x4E>(m, m));   // quad_perm [2,3,0,1]  (lane^2)
        m = fmaxf(m, dpp_mov<0x141>(m, m));  // row_half_mirror      (8-group)
        m = fmaxf(m, dpp_mov<0x140>(m, m));  // row_mirror           (16-group)
        unsigned e = (__float_as_uint(m) >> 23) & 0xFFu;
        float sc = __uint_as_float((254u - e) << 23);  // 2^(127-e), exact
        offE += (int)e - 127;
        P0 *= sc; P1 *= sc; P2 *= sc; F49 *= sc; S *= sc;
    };

    float A00, A01, A02, A10, A11, A12, A20, A21, A22, A30, A31, A32;
    float B00, B01, B02, B10, B11, B12, B20, B21, B22, B30, B31, B32;
    float C00, C01, C02, C10, C11, C12, C20, C21, C22, C30, C31, C32;

#define LOADBUF(X, blk) do {                                   \
        const float* _p = base + (blk) * 192;                  \
        X##00 = _p[0];   X##01 = _p[1];   X##02 = _p[2];       \
        X##10 = _p[48];  X##11 = _p[49];  X##12 = _p[50];      \
        X##20 = _p[96];  X##21 = _p[97];  X##22 = _p[98];      \
        X##30 = _p[144]; X##31 = _p[145]; X##32 = _p[146];     \
    } while (0)

#define DOBLK(X) do {                                          \
        do_row(X##00, X##01, X##02);                           \
        do_row(X##10, X##11, X##12);                           \
        do_row(X##20, X##21, X##22);                           \
        do_row(X##30, X##31, X##32);                           \
    } while (0)

    LOADBUF(A, 0);
    LOADBUF(B, 1);
    LOADBUF(C, 2);

    // ---- Block 0 (buffer A): row 0 is the multiplicative scan ----
    {
        float a0 = fast_exp2(KEXP * A00);
        float a1 = fast_exp2(KEXP * A01);
        float a2 = fast_exp2(KEXP * A02);
        float Ap0 = a0, Ap1 = Ap0 * a1, Ap2 = Ap1 * a2;
        float Ax = Ap2;
        Ax *= dpp_mov<0x111>(Ax, 1.0f);
        Ax *= dpp_mov<0x112>(Ax, 1.0f);
        Ax *= dpp_mov<0x114>(Ax, 1.0f);
        Ax *= dpp_mov<0x118>(Ax, 1.0f);
        float yin = dpp_mov<0x111>(Ax, 1.0f);
        P0 = Ap0 * yin; P1 = Ap1 * yin; P2 = Ap2 * yin;
        F49 = P2;  // pad col: cum[0][49] = cum[0][48]
    }
    do_row(A10, A11, A12); do_row(A20, A21, A22); do_row(A30, A31, A32);
    LOADBUF(A, 3);

    // ---- Blocks 1..11, buffers rotate B,C,A,... renorm after blocks 1,3,5,7,9
#pragma unroll
    for (int r = 0; r < 4; ++r) {
        const int b = 3 * r;  // this iteration computes blocks b+1, b+2, b+3
        {
            DOBLK(B);
            if (((b + 1) & 1) && (b + 1) != 11) renorm();
            if (b + 4 < 12) LOADBUF(B, b + 4);
        }
        if (b + 2 < 12) {
            DOBLK(C);
            if (((b + 2) & 1) && (b + 2) != 11) renorm();
            if (b + 5 < 12) LOADBUF(C, b + 5);
        }
        if (b + 3 < 12) {
            DOBLK(A);
            if (((b + 3) & 1) && (b + 3) != 11) renorm();
            if (b + 6 < 12) LOADBUF(A, b + 6);
        }
    }
#undef LOADBUF
#undef DOBLK

    if (k == 15) {
        // cum = -0.5 * ln(F49_true), F49_true = F49 * 2^offE
        out[prob] = -0.5f * (logf(F49) + (float)offE * 0.6931471805599453f);
    }
}

extern "C" void kernel_launch(void* const* d_in, const int* in_sizes, int n_in,
                              void* d_out, int out_size, void* d_ws, size_t ws_size,
                              hipStream_t stream) {
    const float* dists = (const float*)d_in[0];
    float* out = (float*)d_out;
    // 16384 problems x 16 lanes = 262144 threads; 256/block -> 1024 blocks.
    otam_kernel<<<dim3(1024), dim3(256), 0, stream>>>(dists, out);
}